// Round 10
// baseline (1331.046 us; speedup 1.0000x reference)
//
#include <hip/hip_runtime.h>
#include <stdint.h>

typedef unsigned short u16;
typedef unsigned int u32;
typedef short bf16x8 __attribute__((ext_vector_type(8)));
typedef float f32x4 __attribute__((ext_vector_type(4)));

#define E_ 8
#define H_ 2048
#define F_ 4096
#define T_ 16384
#define TE_ 2048

#define WAITV(n) asm volatile("s_waitcnt vmcnt(" #n ")" ::: "memory")
#define LGKM0 asm volatile("s_waitcnt lgkmcnt(0)" ::: "memory")
#define BARF                       \
  do {                             \
    asm volatile("" ::: "memory"); \
    __builtin_amdgcn_s_barrier();  \
    asm volatile("" ::: "memory"); \
  } while (0)

__device__ __forceinline__ u16 f2bf(float f) {
  u32 u = __builtin_bit_cast(u32, f);
  u32 r = (u + 0x7FFFu + ((u >> 16) & 1u)) >> 16;  // RNE
  return (u16)r;
}

// packed 2xfp32 -> 2xbf16 (RNE); lo16 = first operand
__device__ __forceinline__ u32 cvtpk(float lo, float hi) {
  u32 r;
  asm("v_cvt_pk_bf16_f32 %0, %1, %2" : "=v"(r) : "v"(lo), "v"(hi));
  return r;
}

__device__ __forceinline__ void gload16(const u16* g, u16* l) {
  __builtin_amdgcn_global_load_lds(
      (__attribute__((address_space(1))) void*)g,
      (__attribute__((address_space(3))) void*)l, 16, 0, 0);
}

__device__ __forceinline__ void mfma_b(f32x4& acc, bf16x8 a, bf16x8 b) {
  asm volatile("v_mfma_f32_16x16x32_bf16 %0, %1, %2, %0"
               : "+v"(acc)
               : "v"(a), "v"(b));
}

// ---------- fp32 -> bf16 convert (x only; weights converted in-GEMM) ----

__global__ __launch_bounds__(256) void cvt_kernel(const float* __restrict__ src,
                                                  u16* __restrict__ dst,
                                                  long n4) {
  long i = (long)blockIdx.x * blockDim.x + threadIdx.x;
  long stride = (long)gridDim.x * blockDim.x;
  const float4* s4 = (const float4*)src;
  uint2* d4 = (uint2*)dst;
  for (; i < n4; i += stride) {
    float4 v = s4[i];
    uint2 o;
    o.x = (u32)f2bf(v.x) | ((u32)f2bf(v.y) << 16);
    o.y = (u32)f2bf(v.z) | ((u32)f2bf(v.w) << 16);
    d4[i] = o;
  }
}

// ============ GEMM1 fused: hidden = silu(x@Wg^T) * (x@Wu^T) ============
// Round-8 proven structure (256 thr / 4 waves, tile 128x64h, BK=64, ring-2
// 64 KiB -> 2 blocks/CU, 0-conflict XOR layout), with B (weights) now
// reg-staged DIRECTLY FROM FP32: 8 float4 loads -> v_cvt_pk_bf16_f32 ->
// ds_write_b128 into the identical LDS bytes gload16 used to produce.
// vmcnt ledger: stage issues loadB(8)+stageA(4)=12; W16 drains B(t+1) regs,
// W12 drains A(t+1) dma; tail W4/W0.

__global__ __launch_bounds__(256, 2) void gemm1_silu(
    const u16* __restrict__ Xb, const float* __restrict__ Wgu,
    u16* __restrict__ Hid, long sX, long sW, long sH) {
  const int z = blockIdx.z;
  Xb += (long)z * sX;
  Wgu += (long)z * sW;
  Hid += (long)z * sH;

  const int bx = blockIdx.x;  // hidden-col tile (64)
  const int by = blockIdx.y;  // row tile (128)
  const int tid = threadIdx.x;
  const int w = tid >> 6;  // 0..3
  const int lane = tid & 63;
  const int wr = w >> 1, wc = w & 1;
  const int fr = lane & 15, q = lane >> 4, l7 = lane & 7;

  // per-buf (16384 el = 32 KB): A[128][64] @0, Bg[64][64] @8192, Bu @12288
  __shared__ __attribute__((aligned(16))) u16 lds[2 * 16384];

  const int srow8 = lane >> 3;
  const int sgran = (lane & 7) ^ (lane >> 3);
  const u16* gA = Xb + (size_t)(by * 128 + srow8) * H_ + sgran * 8;
  // fp32 weight base, float4-indexed (row stride H_/4 = 512 f4)
  const float4* gB4 =
      (const float4*)Wgu + (size_t)(bx * 64 + srow8) * (H_ / 4) + sgran * 2;

  auto stageA = [&](int t, int buf) {
    u16* L = lds + buf * 16384;
    const int ko = t * 64;
#pragma unroll
    for (int i = 0; i < 4; ++i) {
      const int c = i * 4 + w;
      gload16(gA + (size_t)(c * 8) * H_ + ko, L + c * 512 + lane * 8);
    }
  };

  // chunk c=i*4+w: c<8 -> gate row bx*64+c*8.., c>=8 -> up (F_ rows later)
  auto loadB = [&](float4* r, int t) {
    const size_t kt = (size_t)t * 16;
#pragma unroll
    for (int i = 0; i < 4; ++i) {
      const int c = i * 4 + w;
      const size_t roff = (i < 2) ? (size_t)c * 8 * (H_ / 4)
                                  : (size_t)F_ * (H_ / 4) +
                                        (size_t)(c - 8) * 8 * (H_ / 4);
      r[2 * i] = gB4[roff + kt];
      r[2 * i + 1] = gB4[roff + kt + 1];
    }
  };

  auto writeB = [&](int buf, const float4* r) {
    u16* L = lds + buf * 16384;
#pragma unroll
    for (int i = 0; i < 4; ++i) {
      const int c = i * 4 + w;
      uint4 v;
      v.x = cvtpk(r[2 * i].x, r[2 * i].y);
      v.y = cvtpk(r[2 * i].z, r[2 * i].w);
      v.z = cvtpk(r[2 * i + 1].x, r[2 * i + 1].y);
      v.w = cvtpk(r[2 * i + 1].z, r[2 * i + 1].w);
      *(uint4*)&L[8192 + c * 512 + lane * 8] = v;
    }
  };

  f32x4 accG[4][2] = {};
  f32x4 accU[4][2] = {};

  auto comp = [&](int buf) {
    const u16* L = lds + buf * 16384;
#pragma unroll
    for (int ks = 0; ks < 2; ++ks) {
      const int seg = (((ks << 2) + q) ^ l7) << 3;
      bf16x8 a[4], bg[2], bu[2];
#pragma unroll
      for (int mi = 0; mi < 4; ++mi)
        a[mi] = *(const bf16x8*)&L[(wr * 64 + mi * 16 + fr) * 64 + seg];
#pragma unroll
      for (int ni = 0; ni < 2; ++ni) {
        bg[ni] = *(const bf16x8*)&L[8192 + (wc * 32 + ni * 16 + fr) * 64 + seg];
        bu[ni] =
            *(const bf16x8*)&L[12288 + (wc * 32 + ni * 16 + fr) * 64 + seg];
      }
      __builtin_amdgcn_s_setprio(1);
#pragma unroll
      for (int mi = 0; mi < 4; ++mi)
#pragma unroll
        for (int ni = 0; ni < 2; ++ni) {
          mfma_b(accG[mi][ni], a[mi], bg[ni]);
          mfma_b(accU[mi][ni], a[mi], bu[ni]);
        }
      __builtin_amdgcn_s_setprio(0);
    }
  };

  float4 rB0[8], rB1[8];
  const int NT = H_ / 64;  // 32
  // prologue: B0(8) A0(4) B1(8) A1(4)
  loadB(rB0, 0);
  stageA(0, 0);
  loadB(rB1, 1);
  stageA(1, 1);
  WAITV(16);  // B0 regs landed
  writeB(0, rB0);
  WAITV(12);  // A0 dma landed
  LGKM0;
  BARF;
  for (int t = 0; t < NT - 2; t += 2) {
    comp(0);
    BARF;
    loadB(rB0, t + 2);
    stageA(t + 2, 0);
    WAITV(16);
    writeB(1, rB1);
    WAITV(12);
    LGKM0;
    BARF;
    comp(1);
    BARF;
    loadB(rB1, t + 3);
    stageA(t + 3, 1);
    WAITV(16);
    writeB(0, rB0);
    WAITV(12);
    LGKM0;
    BARF;
  }
  comp(0);  // tile NT-2
  BARF;
  WAITV(4);  // B(NT-1) regs landed
  writeB(1, rB1);
  WAITV(0);  // A(NT-1) dma landed
  LGKM0;
  BARF;
  comp(1);  // tile NT-1

  const int row0 = by * 128 + wr * 64 + q * 4;
  const int col0 = bx * 64 + wc * 32 + fr;
#pragma unroll
  for (int mi = 0; mi < 4; ++mi)
#pragma unroll
    for (int ni = 0; ni < 2; ++ni)
#pragma unroll
      for (int j = 0; j < 4; ++j) {
        float g = accG[mi][ni][j];
        float u = accU[mi][ni][j];
        float h = (g / (1.f + __expf(-g))) * u;
        Hid[(size_t)(row0 + mi * 16 + j) * F_ + col0 + ni * 16] = f2bf(h);
      }
}

// ============ GEMM2: out = hidden @ w_down^T (fp32 out) ============
// Round-8 proven structure; B (w_down) reg-staged from fp32, A (hidden,
// bf16) via global_load_lds. Same ledger as gemm1.

__global__ __launch_bounds__(256, 2) void gemm2_down(
    const u16* __restrict__ Hd, const float* __restrict__ Wd,
    float* __restrict__ Out, long sH, long sW, long sO) {
  const int z = blockIdx.z;
  Hd += (long)z * sH;
  Wd += (long)z * sW;
  Out += (long)z * sO;

  const int bx = blockIdx.x;  // H-col tile (128)
  const int by = blockIdx.y;  // row tile (128)
  const int tid = threadIdx.x;
  const int w = tid >> 6;
  const int lane = tid & 63;
  const int wr = w >> 1, wc = w & 1;
  const int fr = lane & 15, q = lane >> 4, l7 = lane & 7;

  // per-buf (16384 el = 32 KB): A[128][64] @0, B[128][64] @8192
  __shared__ __attribute__((aligned(16))) u16 lds[2 * 16384];

  const int srow8 = lane >> 3;
  const int sgran = (lane & 7) ^ (lane >> 3);
  const u16* gA = Hd + (size_t)(by * 128 + srow8) * F_ + sgran * 8;
  const float4* gB4 =
      (const float4*)Wd + (size_t)(bx * 128 + srow8) * (F_ / 4) + sgran * 2;

  auto stageA = [&](int t, int buf) {
    u16* L = lds + buf * 16384;
    const int ko = t * 64;
#pragma unroll
    for (int i = 0; i < 4; ++i) {
      const int c = i * 4 + w;
      gload16(gA + (size_t)(c * 8) * F_ + ko, L + c * 512 + lane * 8);
    }
  };

  auto loadB = [&](float4* r, int t) {
    const size_t kt = (size_t)t * 16;
#pragma unroll
    for (int i = 0; i < 4; ++i) {
      const int c = i * 4 + w;
      const size_t roff = (size_t)c * 8 * (F_ / 4);
      r[2 * i] = gB4[roff + kt];
      r[2 * i + 1] = gB4[roff + kt + 1];
    }
  };

  auto writeB = [&](int buf, const float4* r) {
    u16* L = lds + buf * 16384;
#pragma unroll
    for (int i = 0; i < 4; ++i) {
      const int c = i * 4 + w;
      uint4 v;
      v.x = cvtpk(r[2 * i].x, r[2 * i].y);
      v.y = cvtpk(r[2 * i].z, r[2 * i].w);
      v.z = cvtpk(r[2 * i + 1].x, r[2 * i + 1].y);
      v.w = cvtpk(r[2 * i + 1].z, r[2 * i + 1].w);
      *(uint4*)&L[8192 + c * 512 + lane * 8] = v;
    }
  };

  f32x4 acc[4][4] = {};

  auto comp = [&](int buf) {
    const u16* L = lds + buf * 16384;
#pragma unroll
    for (int ks = 0; ks < 2; ++ks) {
      const int seg = (((ks << 2) + q) ^ l7) << 3;
      bf16x8 a[4], b[4];
#pragma unroll
      for (int mi = 0; mi < 4; ++mi)
        a[mi] = *(const bf16x8*)&L[(wr * 64 + mi * 16 + fr) * 64 + seg];
#pragma unroll
      for (int ni = 0; ni < 4; ++ni)
        b[ni] = *(const bf16x8*)&L[8192 + (wc * 64 + ni * 16 + fr) * 64 + seg];
      __builtin_amdgcn_s_setprio(1);
#pragma unroll
      for (int mi = 0; mi < 4; ++mi)
#pragma unroll
        for (int ni = 0; ni < 4; ++ni) mfma_b(acc[mi][ni], a[mi], b[ni]);
      __builtin_amdgcn_s_setprio(0);
    }
  };

  float4 rB0[8], rB1[8];
  const int NT = F_ / 64;  // 64
  loadB(rB0, 0);
  stageA(0, 0);
  loadB(rB1, 1);
  stageA(1, 1);
  WAITV(16);
  writeB(0, rB0);
  WAITV(12);
  LGKM0;
  BARF;
  for (int t = 0; t < NT - 2; t += 2) {
    comp(0);
    BARF;
    loadB(rB0, t + 2);
    stageA(t + 2, 0);
    WAITV(16);
    writeB(1, rB1);
    WAITV(12);
    LGKM0;
    BARF;
    comp(1);
    BARF;
    loadB(rB1, t + 3);
    stageA(t + 3, 1);
    WAITV(16);
    writeB(0, rB0);
    WAITV(12);
    LGKM0;
    BARF;
  }
  comp(0);
  BARF;
  WAITV(4);
  writeB(1, rB1);
  WAITV(0);
  LGKM0;
  BARF;
  comp(1);

  const int row0 = by * 128 + wr * 64 + q * 4;
  const int col0 = bx * 128 + wc * 64 + fr;
#pragma unroll
  for (int mi = 0; mi < 4; ++mi)
#pragma unroll
    for (int ni = 0; ni < 4; ++ni)
#pragma unroll
      for (int j = 0; j < 4; ++j)
        Out[(size_t)(row0 + mi * 16 + j) * H_ + col0 + ni * 16] =
            acc[mi][ni][j];
}

// ---------- host ----------

extern "C" void kernel_launch(void* const* d_in, const int* in_sizes, int n_in,
                              void* d_out, int out_size, void* d_ws,
                              size_t ws_size, hipStream_t stream) {
  (void)in_sizes;
  (void)n_in;
  (void)out_size;
  const float* x = (const float*)d_in[0];
  const float* wgu = (const float*)d_in[1];
  const float* wdn = (const float*)d_in[2];
  float* out = (float*)d_out;
  u16* ws = (u16*)d_ws;

  const size_t xbN = (size_t)T_ * H_;   // bf16 x
  const size_t hidN = (size_t)T_ * F_;  // bf16 hidden
  const size_t fullBytes = (xbN + hidN) * 2;  // 192 MiB

  dim3 cblk(256), gblk(256);

  if (ws_size >= fullBytes) {
    u16* xb = ws;
    u16* hid = xb + xbN;
    cvt_kernel<<<1024, cblk, 0, stream>>>(x, xb, (long)(xbN / 4));
    gemm1_silu<<<dim3(F_ / 64, TE_ / 128, E_), gblk, 0, stream>>>(
        xb, wgu, hid, (long)TE_ * H_, (long)2 * F_ * H_, (long)TE_ * F_);
    gemm2_down<<<dim3(H_ / 128, TE_ / 128, E_), gblk, 0, stream>>>(
        hid, wdn, out, (long)TE_ * F_, (long)H_ * F_, (long)TE_ * H_);
  } else {
    // per-expert fallback (24 MiB ws)
    u16* xb = ws;
    u16* hid = xb + (size_t)TE_ * H_;
    for (int e = 0; e < E_; ++e) {
      cvt_kernel<<<512, cblk, 0, stream>>>(x + (size_t)e * TE_ * H_, xb,
                                           (long)((size_t)TE_ * H_ / 4));
      gemm1_silu<<<dim3(F_ / 64, TE_ / 128, 1), gblk, 0, stream>>>(
          xb, wgu + (size_t)e * 2 * F_ * H_, hid, 0, 0, 0);
      gemm2_down<<<dim3(H_ / 128, TE_ / 128, 1), gblk, 0, stream>>>(
          hid, wdn + (size_t)e * H_ * F_, out + (size_t)e * TE_ * H_, 0, 0, 0);
    }
  }
}